// Round 1
// baseline (322.252 us; speedup 1.0000x reference)
//
#include <hip/hip_runtime.h>

// R-GCN layer: out[n] = rsqrt(in_deg[n]) * sum_{e: dst=n} W[order[e]] @ (feat[src[e]] * rsqrt(out_deg[src[e]])) + bias
// Strategy: bucket edges by relation; one wave per edge-stream with W (64x64) held in
// VGPRs (lane o = output row o); h broadcast via per-wave LDS slot; fp32 atomicAdd into out.

constexpr int N_NODES = 10000;
constexpr int N_EDGES = 100000;
constexpr int F = 64;           // in = out feats
constexpr int R = 10;           // edge types
constexpr int BLOCK = 256;
constexpr int EDGE_BLOCKS = 512;
constexpr int G_WAVES = EDGE_BLOCKS * (BLOCK / 64);  // 2048

__global__ void k_count(const int* __restrict__ src, const int* __restrict__ dst,
                        const int* __restrict__ order,
                        float* deg_out, float* deg_in, int* rel_cnt, int* rank) {
    int e = blockIdx.x * BLOCK + threadIdx.x;
    int lane = threadIdx.x & 63;
    int r = -1;
    if (e < N_EDGES) {
        atomicAdd(&deg_out[src[e]], 1.0f);
        atomicAdd(&deg_in[dst[e]], 1.0f);
        r = order[e];
    }
    int myrank = 0;
#pragma unroll
    for (int rr = 0; rr < R; ++rr) {
        unsigned long long m = __ballot(r == rr);
        if (m == 0ull) continue;
        int leader = __ffsll((long long)m) - 1;
        int base = 0;
        if (lane == leader) base = atomicAdd(&rel_cnt[rr], __popcll(m));
        base = __shfl(base, leader);
        if (r == rr) myrank = base + __popcll(m & ((1ull << lane) - 1ull));
    }
    if (e < N_EDGES) rank[e] = myrank;
}

__global__ void k_scan(const int* __restrict__ rel_cnt, int* rel_off, int* rel_woff) {
    if (threadIdx.x == 0) {
        int off = 0;
        for (int r = 0; r < R; ++r) { rel_off[r] = off; off += rel_cnt[r]; }
        rel_off[R] = off;  // == N_EDGES
        for (int r = 0; r <= R; ++r)
            rel_woff[r] = (int)((long long)rel_off[r] * G_WAVES / N_EDGES);
    }
}

__global__ void k_scatter(const int* __restrict__ order, const int* __restrict__ rank,
                          const int* __restrict__ rel_off, int* __restrict__ perm) {
    int e = blockIdx.x * BLOCK + threadIdx.x;
    if (e < N_EDGES) perm[rel_off[order[e]] + rank[e]] = e;
}

__global__ __launch_bounds__(BLOCK) void k_edge(
    const float* __restrict__ feat, const int* __restrict__ src,
    const int* __restrict__ dst, const float* __restrict__ emb,
    const float* __restrict__ deg_out, const int* __restrict__ rel_off,
    const int* __restrict__ rel_woff, const int* __restrict__ perm,
    float* __restrict__ out) {
    __shared__ float hbuf[BLOCK / 64][F];
    int lane = threadIdx.x & 63;
    int wib = threadIdx.x >> 6;
    int g = blockIdx.x * (BLOCK / 64) + wib;
    float* hb = hbuf[wib];

    for (int r = 0; r < R; ++r) {
        int w0 = rel_woff[r], w1 = rel_woff[r + 1];
        int nw = w1 - w0, lw;
        if (nw == 0) {               // tiny bucket got 0 waves: its boundary wave covers it alone
            if (g != w0) continue;
            lw = 0; nw = 1;
        } else {
            if (g < w0 || g >= w1) continue;
            lw = g - w0;
        }
        int e0 = rel_off[r], e1 = rel_off[r + 1];
        if (e0 + lw >= e1) continue;

        // Load this relation's W: lane o holds row o (64 floats) in VGPRs.
        float wreg[F];
        const float4* wr4 = (const float4*)(emb + (size_t)r * F * F + lane * F);
#pragma unroll
        for (int k4 = 0; k4 < F / 4; ++k4) {
            float4 t = wr4[k4];
            wreg[4 * k4 + 0] = t.x; wreg[4 * k4 + 1] = t.y;
            wreg[4 * k4 + 2] = t.z; wreg[4 * k4 + 3] = t.w;
        }

        for (int idx = e0 + lw; idx < e1; idx += nw) {
            int e = perm[idx];
            int s = src[e], d = dst[e];
            float rn = rsqrtf(fmaxf(deg_out[s], 1.0f));
            float h = feat[(size_t)s * F + lane] * rn;   // coalesced 256B, L2-resident
            hb[lane] = h;                                 // wave-private LDS slot (2-way, free)
            float acc = 0.f;
            const float4* hb4 = (const float4*)hb;
#pragma unroll
            for (int k4 = 0; k4 < F / 4; ++k4) {
                float4 hv = hb4[k4];                      // broadcast read
                acc = fmaf(wreg[4 * k4 + 0], hv.x, acc);
                acc = fmaf(wreg[4 * k4 + 1], hv.y, acc);
                acc = fmaf(wreg[4 * k4 + 2], hv.z, acc);
                acc = fmaf(wreg[4 * k4 + 3], hv.w, acc);
            }
            atomicAdd(&out[(size_t)d * F + lane], acc);   // contiguous 256B per wave
        }
    }
}

__global__ void k_final(const float* __restrict__ deg_in, const float* __restrict__ bias,
                        float* __restrict__ out) {
    int t = blockIdx.x * BLOCK + threadIdx.x;
    if (t < N_NODES * F) {
        int n = t >> 6, o = t & 63;
        out[t] = out[t] * rsqrtf(fmaxf(deg_in[n], 1.0f)) + bias[o];
    }
}

extern "C" void kernel_launch(void* const* d_in, const int* in_sizes, int n_in,
                              void* d_out, int out_size, void* d_ws, size_t ws_size,
                              hipStream_t stream) {
    const float* feat  = (const float*)d_in[0];
    const int*   src   = (const int*)d_in[1];
    const int*   dst   = (const int*)d_in[2];
    const int*   order = (const int*)d_in[3];
    const float* emb   = (const float*)d_in[4];
    const float* bias  = (const float*)d_in[5];
    float* out = (float*)d_out;

    // Workspace layout
    float* deg_out  = (float*)d_ws;              // N_NODES
    float* deg_in   = deg_out + N_NODES;         // N_NODES
    int*   rel_cnt  = (int*)(deg_in + N_NODES);  // 16
    int*   rel_off  = rel_cnt + 16;              // 16 (11 used)
    int*   rel_woff = rel_off + 16;              // 16 (11 used)
    int*   rank     = rel_woff + 16;             // N_EDGES
    int*   perm     = rank + N_EDGES;            // N_EDGES

    size_t zbytes = (size_t)(2 * N_NODES + 16) * sizeof(float);  // deg_out, deg_in, rel_cnt
    hipMemsetAsync(d_ws, 0, zbytes, stream);
    hipMemsetAsync(d_out, 0, (size_t)out_size * sizeof(float), stream);

    int eb = (N_EDGES + BLOCK - 1) / BLOCK;
    k_count<<<eb, BLOCK, 0, stream>>>(src, dst, order, deg_out, deg_in, rel_cnt, rank);
    k_scan<<<1, 64, 0, stream>>>(rel_cnt, rel_off, rel_woff);
    k_scatter<<<eb, BLOCK, 0, stream>>>(order, rank, rel_off, perm);
    k_edge<<<EDGE_BLOCKS, BLOCK, 0, stream>>>(feat, src, dst, emb, deg_out,
                                              rel_off, rel_woff, perm, out);
    k_final<<<(N_NODES * F + BLOCK - 1) / BLOCK, BLOCK, 0, stream>>>(deg_in, bias, out);
}

// Round 2
// 148.732 us; speedup vs baseline: 2.1667x; 2.1667x over previous
//
#include <hip/hip_runtime.h>

// R-GCN layer: out[n] = rsqrt(in_deg[n]) * sum_{e: dst=n} W[order[e]] @ (feat[src[e]] * rsqrt(out_deg[src[e]])) + bias
// R2: int degree atomics (native, no CAS loop); per-block LDS relation histogram
// (10 global atomics/block instead of 10/wave); unsafeAtomicAdd (HW global_atomic_add_f32)
// for the output scatter instead of the fp32 CAS loop.

constexpr int N_NODES = 10000;
constexpr int N_EDGES = 100000;
constexpr int F = 64;           // in = out feats
constexpr int R = 10;           // edge types
constexpr int BLOCK = 256;
constexpr int EDGE_BLOCKS = 512;
constexpr int G_WAVES = EDGE_BLOCKS * (BLOCK / 64);  // 2048

__global__ void k_count(const int* __restrict__ src, const int* __restrict__ dst,
                        const int* __restrict__ order,
                        int* deg_out, int* deg_in, int* rel_cnt, int* rank) {
    __shared__ int hist[R], base[R];
    int tid = threadIdx.x;
    int e = blockIdx.x * BLOCK + tid;
    if (tid < R) hist[tid] = 0;
    __syncthreads();
    int r = -1, lr = 0;
    if (e < N_EDGES) {
        atomicAdd(&deg_out[src[e]], 1);      // native int atomic
        atomicAdd(&deg_in[dst[e]], 1);
        r = order[e];
        lr = atomicAdd(&hist[r], 1);         // LDS atomic: intra-block rank
    }
    __syncthreads();
    if (tid < R) base[tid] = hist[tid] ? atomicAdd(&rel_cnt[tid], hist[tid]) : 0;
    __syncthreads();
    if (e < N_EDGES) rank[e] = base[r] + lr;
}

__global__ void k_scan(const int* __restrict__ rel_cnt, int* rel_off, int* rel_woff) {
    if (threadIdx.x == 0) {
        int off = 0;
        for (int r = 0; r < R; ++r) { rel_off[r] = off; off += rel_cnt[r]; }
        rel_off[R] = off;  // == N_EDGES
        for (int r = 0; r <= R; ++r)
            rel_woff[r] = (int)((long long)rel_off[r] * G_WAVES / N_EDGES);
    }
}

__global__ void k_scatter(const int* __restrict__ order, const int* __restrict__ rank,
                          const int* __restrict__ rel_off, int* __restrict__ perm) {
    int e = blockIdx.x * BLOCK + threadIdx.x;
    if (e < N_EDGES) perm[rel_off[order[e]] + rank[e]] = e;
}

__global__ __launch_bounds__(BLOCK) void k_edge(
    const float* __restrict__ feat, const int* __restrict__ src,
    const int* __restrict__ dst, const float* __restrict__ emb,
    const int* __restrict__ deg_out, const int* __restrict__ rel_off,
    const int* __restrict__ rel_woff, const int* __restrict__ perm,
    float* __restrict__ out) {
    __shared__ float hbuf[BLOCK / 64][F];
    int lane = threadIdx.x & 63;
    int wib = threadIdx.x >> 6;
    int g = blockIdx.x * (BLOCK / 64) + wib;
    float* hb = hbuf[wib];

    for (int r = 0; r < R; ++r) {
        int w0 = rel_woff[r], w1 = rel_woff[r + 1];
        int nw = w1 - w0, lw;
        if (nw == 0) {               // tiny bucket got 0 waves: boundary wave covers it alone
            if (g != w0) continue;
            lw = 0; nw = 1;
        } else {
            if (g < w0 || g >= w1) continue;
            lw = g - w0;
        }
        int e0 = rel_off[r], e1 = rel_off[r + 1];
        if (e0 + lw >= e1) continue;

        // Load this relation's W: lane o holds row o (64 floats) in VGPRs.
        float wreg[F];
        const float4* wr4 = (const float4*)(emb + (size_t)r * F * F + lane * F);
#pragma unroll
        for (int k4 = 0; k4 < F / 4; ++k4) {
            float4 t = wr4[k4];
            wreg[4 * k4 + 0] = t.x; wreg[4 * k4 + 1] = t.y;
            wreg[4 * k4 + 2] = t.z; wreg[4 * k4 + 3] = t.w;
        }

        for (int idx = e0 + lw; idx < e1; idx += nw) {
            int e = perm[idx];
            int s = src[e], d = dst[e];
            float rn = rsqrtf((float)max(deg_out[s], 1));
            float h = feat[(size_t)s * F + lane] * rn;   // coalesced 256B, L2-resident
            hb[lane] = h;                                 // wave-private LDS slot (2-way, free)
            float acc = 0.f;
            const float4* hb4 = (const float4*)hb;
#pragma unroll
            for (int k4 = 0; k4 < F / 4; ++k4) {
                float4 hv = hb4[k4];                      // broadcast read
                acc = fmaf(wreg[4 * k4 + 0], hv.x, acc);
                acc = fmaf(wreg[4 * k4 + 1], hv.y, acc);
                acc = fmaf(wreg[4 * k4 + 2], hv.z, acc);
                acc = fmaf(wreg[4 * k4 + 3], hv.w, acc);
            }
            // HW fp32 atomic (global_atomic_add_f32), not the CAS loop.
            unsafeAtomicAdd(&out[(size_t)d * F + lane], acc);
        }
    }
}

__global__ void k_final(const int* __restrict__ deg_in, const float* __restrict__ bias,
                        float* __restrict__ out) {
    int t = blockIdx.x * BLOCK + threadIdx.x;
    if (t < N_NODES * F) {
        int n = t >> 6, o = t & 63;
        out[t] = out[t] * rsqrtf((float)max(deg_in[n], 1)) + bias[o];
    }
}

extern "C" void kernel_launch(void* const* d_in, const int* in_sizes, int n_in,
                              void* d_out, int out_size, void* d_ws, size_t ws_size,
                              hipStream_t stream) {
    const float* feat  = (const float*)d_in[0];
    const int*   src   = (const int*)d_in[1];
    const int*   dst   = (const int*)d_in[2];
    const int*   order = (const int*)d_in[3];
    const float* emb   = (const float*)d_in[4];
    const float* bias  = (const float*)d_in[5];
    float* out = (float*)d_out;

    // Workspace layout
    int* deg_out  = (int*)d_ws;                  // N_NODES
    int* deg_in   = deg_out + N_NODES;           // N_NODES
    int* rel_cnt  = deg_in + N_NODES;            // 16
    int* rel_off  = rel_cnt + 16;                // 16 (11 used)
    int* rel_woff = rel_off + 16;                // 16 (11 used)
    int* rank     = rel_woff + 16;               // N_EDGES
    int* perm     = rank + N_EDGES;              // N_EDGES

    size_t zbytes = (size_t)(2 * N_NODES + 16) * sizeof(int);  // deg_out, deg_in, rel_cnt
    hipMemsetAsync(d_ws, 0, zbytes, stream);
    hipMemsetAsync(d_out, 0, (size_t)out_size * sizeof(float), stream);

    int eb = (N_EDGES + BLOCK - 1) / BLOCK;
    k_count<<<eb, BLOCK, 0, stream>>>(src, dst, order, deg_out, deg_in, rel_cnt, rank);
    k_scan<<<1, 64, 0, stream>>>(rel_cnt, rel_off, rel_woff);
    k_scatter<<<eb, BLOCK, 0, stream>>>(order, rank, rel_off, perm);
    k_edge<<<EDGE_BLOCKS, BLOCK, 0, stream>>>(feat, src, dst, emb, deg_out,
                                              rel_off, rel_woff, perm, out);
    k_final<<<(N_NODES * F + BLOCK - 1) / BLOCK, BLOCK, 0, stream>>>(deg_in, bias, out);
}

// Round 3
// 130.238 us; speedup vs baseline: 2.4743x; 1.1420x over previous
//
#include <hip/hip_runtime.h>

// R-GCN layer: out[n] = rsqrt(in_deg[n]) * sum_{e: dst=n} W[order[e]] @ (feat[src[e]] * rsqrt(out_deg[src[e]])) + bias
// R3: pin W[64] in VGPRs via empty asm (R2 showed VGPR_Count=48 -> compiler was
// re-loading W per edge); 2-edge ILP with 2 accumulator chains each; precompute
// normalized featn once; grid 1024 blocks (16 waves/CU); fuse scan into k_count
// last block and scatter+featn into k_prep (9 -> 6 graph ops).

constexpr int N_NODES = 10000;
constexpr int N_EDGES = 100000;
constexpr int F = 64;           // in = out feats
constexpr int R = 10;           // edge types
constexpr int BLOCK = 256;
constexpr int WPB = BLOCK / 64;
constexpr int EDGE_BLOCKS = 1024;
constexpr int G_WAVES = EDGE_BLOCKS * WPB;  // 4096

__global__ void k_count(const int* __restrict__ src, const int* __restrict__ dst,
                        const int* __restrict__ order,
                        int* deg_out, int* deg_in, int* rel_cnt, int* rank,
                        int* done, int* rel_off, int* rel_woff) {
    __shared__ int hist[R], base[R];
    int tid = threadIdx.x;
    int e = blockIdx.x * BLOCK + tid;
    if (tid < R) hist[tid] = 0;
    __syncthreads();
    int r = -1, lr = 0;
    if (e < N_EDGES) {
        atomicAdd(&deg_out[src[e]], 1);      // native int atomic, fire-and-forget
        atomicAdd(&deg_in[dst[e]], 1);
        r = order[e];
        lr = atomicAdd(&hist[r], 1);         // LDS atomic: intra-block rank
    }
    __syncthreads();
    if (tid < R) base[tid] = hist[tid] ? atomicAdd(&rel_cnt[tid], hist[tid]) : 0;
    __syncthreads();
    if (e < N_EDGES) rank[e] = base[r] + lr;

    // fused scan: last block to finish computes rel_off / rel_woff
    if (tid == 0) {
        __threadfence();
        if (atomicAdd(done, 1) == (int)gridDim.x - 1) {
            int off = 0;
            for (int rr = 0; rr < R; ++rr) {
                int c = atomicAdd(&rel_cnt[rr], 0);   // coherent read
                rel_off[rr] = off; off += c;
            }
            rel_off[R] = off;                          // == N_EDGES
            for (int rr = 0; rr <= R; ++rr)
                rel_woff[rr] = (int)((long long)rel_off[rr] * G_WAVES / N_EDGES);
        }
    }
}

// scatter perm + precompute featn = feat * rsqrt(out_deg)
__global__ void k_prep(const int* __restrict__ order, const int* __restrict__ rank,
                       const int* __restrict__ rel_off, const int* __restrict__ deg_out,
                       const float* __restrict__ feat,
                       int* __restrict__ perm, float* __restrict__ featn) {
    int t = blockIdx.x * BLOCK + threadIdx.x;
    if (t < N_NODES * F)
        featn[t] = feat[t] * rsqrtf((float)max(deg_out[t >> 6], 1));
    if (t < N_EDGES)
        perm[rel_off[order[t]] + rank[t]] = t;
}

__global__ __launch_bounds__(BLOCK) void k_edge(
    const float* __restrict__ featn, const int* __restrict__ src,
    const int* __restrict__ dst, const float* __restrict__ emb,
    const int* __restrict__ rel_off, const int* __restrict__ rel_woff,
    const int* __restrict__ perm, float* __restrict__ out) {
    __shared__ float hbuf[WPB][2][F];
    int lane = threadIdx.x & 63;
    int wib = threadIdx.x >> 6;
    int g = blockIdx.x * WPB + wib;
    float* hA = hbuf[wib][0];
    float* hB = hbuf[wib][1];

    for (int r = 0; r < R; ++r) {
        int w0 = rel_woff[r], w1 = rel_woff[r + 1];
        int nw = w1 - w0, lw;
        if (nw == 0) {               // tiny bucket got 0 waves: boundary wave covers it alone
            if (g != w0) continue;
            lw = 0; nw = 1;
        } else {
            if (g < w0 || g >= w1) continue;
            lw = g - w0;
        }
        int e0 = rel_off[r], e1 = rel_off[r + 1];
        if (e0 + lw >= e1) continue;

        // Load this relation's W: lane o holds row o (64 floats) in VGPRs.
        float wreg[F];
        const float4* wr4 = (const float4*)(emb + (size_t)r * F * F + lane * F);
#pragma unroll
        for (int k4 = 0; k4 < F / 4; ++k4) {
            float4 t = wr4[k4];
            wreg[4 * k4 + 0] = t.x; wreg[4 * k4 + 1] = t.y;
            wreg[4 * k4 + 2] = t.z; wreg[4 * k4 + 3] = t.w;
        }
        // Pin W in VGPRs: opaque asm stops the allocator rematerializing the
        // loads inside the edge loop (R2: VGPR_Count=48 proved it was reloading).
#pragma unroll
        for (int i = 0; i < F; ++i) asm volatile("" : "+v"(wreg[i]));

        for (int idx = e0 + lw; idx < e1; idx += 2 * nw) {
            int idxB = idx + nw;
            bool hasB = idxB < e1;
            int eA = perm[idx];
            int eB = perm[hasB ? idxB : idx];
            int sA = src[eA], dA = dst[eA];
            int sB = src[eB], dB = dst[eB];
            hA[lane] = featn[(size_t)sA * F + lane];   // coalesced 256B, L2-resident
            hB[lane] = featn[(size_t)sB * F + lane];
            float a0 = 0.f, a1 = 0.f, b0 = 0.f, b1 = 0.f;  // 4 indep FMA chains
            const float4* hA4 = (const float4*)hA;
            const float4* hB4 = (const float4*)hB;
#pragma unroll
            for (int k4 = 0; k4 < 8; ++k4) {
                float4 va = hA4[k4];                   // broadcast reads (conflict-free)
                a0 = fmaf(wreg[4 * k4 + 0], va.x, a0);
                a0 = fmaf(wreg[4 * k4 + 1], va.y, a0);
                a0 = fmaf(wreg[4 * k4 + 2], va.z, a0);
                a0 = fmaf(wreg[4 * k4 + 3], va.w, a0);
                float4 va2 = hA4[k4 + 8];
                a1 = fmaf(wreg[32 + 4 * k4 + 0], va2.x, a1);
                a1 = fmaf(wreg[32 + 4 * k4 + 1], va2.y, a1);
                a1 = fmaf(wreg[32 + 4 * k4 + 2], va2.z, a1);
                a1 = fmaf(wreg[32 + 4 * k4 + 3], va2.w, a1);
                float4 vb = hB4[k4];
                b0 = fmaf(wreg[4 * k4 + 0], vb.x, b0);
                b0 = fmaf(wreg[4 * k4 + 1], vb.y, b0);
                b0 = fmaf(wreg[4 * k4 + 2], vb.z, b0);
                b0 = fmaf(wreg[4 * k4 + 3], vb.w, b0);
                float4 vb2 = hB4[k4 + 8];
                b1 = fmaf(wreg[32 + 4 * k4 + 0], vb2.x, b1);
                b1 = fmaf(wreg[32 + 4 * k4 + 1], vb2.y, b1);
                b1 = fmaf(wreg[32 + 4 * k4 + 2], vb2.z, b1);
                b1 = fmaf(wreg[32 + 4 * k4 + 3], vb2.w, b1);
            }
            // HW fp32 atomic (global_atomic_add_f32), wave-contiguous 256B
            unsafeAtomicAdd(&out[(size_t)dA * F + lane], a0 + a1);
            if (hasB) unsafeAtomicAdd(&out[(size_t)dB * F + lane], b0 + b1);
        }
    }
}

__global__ void k_final(const int* __restrict__ deg_in, const float* __restrict__ bias,
                        float* __restrict__ out) {
    int t = blockIdx.x * BLOCK + threadIdx.x;     // indexes float4
    if (t < N_NODES * F / 4) {
        int n = t >> 4, o4 = t & 15;
        float s = rsqrtf((float)max(deg_in[n], 1));
        float4 v = ((float4*)out)[t];
        float4 b = ((const float4*)bias)[o4];
        v.x = v.x * s + b.x; v.y = v.y * s + b.y;
        v.z = v.z * s + b.z; v.w = v.w * s + b.w;
        ((float4*)out)[t] = v;
    }
}

extern "C" void kernel_launch(void* const* d_in, const int* in_sizes, int n_in,
                              void* d_out, int out_size, void* d_ws, size_t ws_size,
                              hipStream_t stream) {
    const float* feat  = (const float*)d_in[0];
    const int*   src   = (const int*)d_in[1];
    const int*   dst   = (const int*)d_in[2];
    const int*   order = (const int*)d_in[3];
    const float* emb   = (const float*)d_in[4];
    const float* bias  = (const float*)d_in[5];
    float* out = (float*)d_out;

    // Workspace layout
    int*   deg_out  = (int*)d_ws;                // N_NODES
    int*   deg_in   = deg_out + N_NODES;         // N_NODES
    int*   rel_cnt  = deg_in + N_NODES;          // 16
    int*   done     = rel_cnt + 16;              // 16
    int*   rel_off  = done + 16;                 // 16 (11 used)
    int*   rel_woff = rel_off + 16;              // 16 (11 used)
    int*   rank     = rel_woff + 16;             // N_EDGES
    int*   perm     = rank + N_EDGES;            // N_EDGES
    float* featn    = (float*)(perm + N_EDGES);  // N_NODES*F

    size_t zbytes = (size_t)(2 * N_NODES + 32) * sizeof(int);  // deg arrays + rel_cnt + done
    hipMemsetAsync(d_ws, 0, zbytes, stream);
    hipMemsetAsync(d_out, 0, (size_t)out_size * sizeof(float), stream);

    int eb = (N_EDGES + BLOCK - 1) / BLOCK;
    k_count<<<eb, BLOCK, 0, stream>>>(src, dst, order, deg_out, deg_in,
                                      rel_cnt, rank, done, rel_off, rel_woff);
    int pb = (N_NODES * F + BLOCK - 1) / BLOCK;
    k_prep<<<pb, BLOCK, 0, stream>>>(order, rank, rel_off, deg_out, feat, perm, featn);
    k_edge<<<EDGE_BLOCKS, BLOCK, 0, stream>>>(featn, src, dst, emb,
                                              rel_off, rel_woff, perm, out);
    k_final<<<(N_NODES * F / 4 + BLOCK - 1) / BLOCK, BLOCK, 0, stream>>>(deg_in, bias, out);
}